// Round 11
// baseline (175.413 us; speedup 1.0000x reference)
//
#include <hip/hip_runtime.h>
#include <hip/hip_bf16.h>

typedef __bf16 bf16x8 __attribute__((ext_vector_type(8)));
typedef float f32x4 __attribute__((ext_vector_type(4)));
typedef float f32x16 __attribute__((ext_vector_type(16)));

__device__ __forceinline__ void load_lds16(const void* g, void* l) {
  __builtin_amdgcn_global_load_lds((const __attribute__((address_space(1))) void*)g,
                                   (__attribute__((address_space(3))) void*)l, 16, 0, 0);
}

// ---------- prep_x: f32 NCHW -> bf16 padded [b][grp4][98][98][32ic], border-zero fused ----------
__global__ __launch_bounds__(512) void prep_x_kernel(const float* __restrict__ x,
                                                     __hip_bfloat16* __restrict__ xn) {
  __shared__ float tile[128][97];
  int h = blockIdx.x;   // 0..95
  int b = blockIdx.y;   // 0..31
  const float* src = x + (size_t)b * 128 * 9216 + h * 96;
  for (int f = threadIdx.x; f < 3072; f += 512) {   // 128 ic x 24 float4
    int ic = f / 24, w4 = f - ic * 24;
    float4 v = *(const float4*)(src + (size_t)ic * 9216 + w4 * 4);
    tile[ic][w4 * 4 + 0] = v.x; tile[ic][w4 * 4 + 1] = v.y;
    tile[ic][w4 * 4 + 2] = v.z; tile[ic][w4 * 4 + 3] = v.w;
  }
  __syncthreads();
  __hip_bfloat16* bb  = xn + (size_t)b * 4 * 307328;
  __hip_bfloat16* dst = bb + (h + 1) * 3136 + 32;
  for (int o = threadIdx.x; o < 1536; o += 512) {   // 16B units
    int grp = o / 384, rem = o - grp * 384;
    int w = rem >> 2, chunk = rem & 3;
    __hip_bfloat16 tmp[8];
    #pragma unroll
    for (int e = 0; e < 8; e++) tmp[e] = __float2bfloat16(tile[grp * 32 + chunk * 8 + e][w]);
    *(uint4*)(dst + (size_t)grp * 307328 + w * 32 + chunk * 8) = *(uint4*)tmp;
  }
  // left/right halo cells of this row (ph = h+1)
  if (threadIdx.x < 32) {
    int u = threadIdx.x;
    int grp = u >> 3, rem = u & 7;
    int pw = (rem >> 2) ? 97 : 0, k = rem & 3;
    *(uint4*)(bb + (size_t)grp * 307328 + ((h + 1) * 98 + pw) * 32 + k * 8) = make_uint4(0, 0, 0, 0);
  }
  // top/bottom halo rows
  if (h == 0 || h == 95) {
    int ph = (h == 0) ? 0 : 97;
    for (int u = threadIdx.x; u < 1568; u += 512) {
      int grp = u / 392, rem = u - grp * 392;
      int pw = rem >> 2, k = rem & 3;
      *(uint4*)(bb + (size_t)grp * 307328 + (ph * 98 + pw) * 32 + k * 8) = make_uint4(0, 0, 0, 0);
    }
  }
}

// ---------- prep_w fused: z projections + merge -> Wt[b][grp4][dx3][dy3][oc128][32ic] ----------
__global__ __launch_bounds__(256) void prep_w_kernel(
    const float* __restrict__ z, const float* __restrict__ gw,
    const float* __restrict__ pww, const float* __restrict__ dww,
    const float* __restrict__ base, __hip_bfloat16* __restrict__ Wt) {
  __shared__ float zs[2048];
  __shared__ float res[138][33];   // row 0=gate, 1..9=dw taps, 10..137=pw ic
  int oc = blockIdx.x;             // 0..127
  for (int i = threadIdx.x; i < 2048; i += 256) zs[i] = z[i];
  __syncthreads();
  int row = threadIdx.x;
  if (row < 138) {
    const float* wrow = (row == 0) ? gw + (size_t)oc * 64
                      : (row < 10) ? dww + ((size_t)oc * 9 + (row - 1)) * 64
                                   : pww + ((size_t)oc * 128 + (row - 10)) * 64;
    float wr[64];
    #pragma unroll
    for (int i = 0; i < 16; i++) {
      float4 v = ((const float4*)wrow)[i];
      wr[4*i] = v.x; wr[4*i+1] = v.y; wr[4*i+2] = v.z; wr[4*i+3] = v.w;
    }
    for (int b = 0; b < 32; b++) {
      float a = 0.f;
      #pragma unroll
      for (int i = 0; i < 64; i++) a += zs[b * 64 + i] * wr[i];
      res[row][b] = a;
    }
  }
  __syncthreads();
  for (int e = threadIdx.x; e < 18432; e += 256) {   // bf162 units
    int icp = e & 15;
    int r1 = e >> 4;
    int tap = r1 % 9, bg = r1 / 9;       // bg = b*4+grp
    int grp = bg & 3, b = bg >> 2;
    int ic = grp * 32 + icp * 2;
    int dy = tap / 3, dx = tap - dy * 3;
    float g = res[0][b], d = res[1 + tap][b];
    float p0 = res[10 + ic][b], p1 = res[11 + ic][b];
    const float* bp = base + ((size_t)(oc * 128 + ic)) * 9 + tap;
    __hip_bfloat162 o2 = {__float2bfloat16(bp[0] * g + p0 * d),
                          __float2bfloat16(bp[9] * g + p1 * d)};
    // slot = dx*3 + dy  (dx-major for dx-outer conv phases)
    *(__hip_bfloat162*)(Wt + (((size_t)bg * 9 + dx * 3 + dy) * 128 + oc) * 32 + icp * 2) = o2;
  }
}

// ---------- conv: 192px x 128oc per block, 96x64 waves, 32x32x16 MFMA ----------
// Fully software-pipelined: weights reg-staged lag-1; A-frags rr0-2 prefetched
// (afrP dbuf) during previous phase, rr3-4 (afrC) loaded at phase top.
// Boundary barrier at end of dx=1 (2-phase x cover), counted waits only.
__global__ __launch_bounds__(256, 2) void conv_kernel(
    const __hip_bfloat16* __restrict__ xn, const __hip_bfloat16* __restrict__ Wt,
    float* __restrict__ out) {
  __shared__ __align__(16) char smem[34816];   // 2 x 17408 B x-tiles

  int bid = blockIdx.x;
  int X = bid & 7, q = bid >> 3;       // XCD pin: 192 blocks (4 samples) per XCD
  int logical = X * 192 + q;
  int b   = logical / 48;
  int rem = logical - b * 48;
  int hr  = rem / 3;
  int wc  = rem - hr * 3;
  int h0 = hr * 6, w0 = wc * 32;

  int tid = threadIdx.x;
  int lane = tid & 63, wid = tid >> 6;
  int l31 = lane & 31, lh = lane >> 5;
  int wm = wid >> 1, wn = wid & 1;

  char* const xr0 = smem;
  char* const xr1 = smem + 17408;
  // per-lane A-read bases: + rr*2176 + kk*1088 + dx*16
  const char* xp0 = xr0 + wm * 3 * 2176 + l31 * 16 + lh * 544;
  const char* xp1 = xr1 + wm * 3 * 2176 + l31 * 16 + lh * 544;

  // x-stage source offsets (chunk-major slot t -> (hh, k, ww)); tail duplicated by all waves
  int xoff[5];
  #pragma unroll
  for (int j = 0; j < 5; j++) {
    int t = (j < 4) ? (j * 256 + tid) : (1024 + lane);
    int hh = t / 136, r2 = t - hh * 136;
    int k = r2 / 34, ww = r2 - k * 34;
    xoff[j] = ((h0 + hh) * 98 + (w0 + ww)) * 32 + k * 8;
  }

  const __hip_bfloat16* xbase = xn + (size_t)b * 4 * 307328;
  // per-lane weight base: lane reads oc = wn*64 + j*32 + l31, ic chunk (kk*2+lh)*8
  const __hip_bfloat16* wlb = Wt + (size_t)b * 147456 + (wn * 64 + l31) * 32 + lh * 8;

  f32x16 acc[3][2];
  #pragma unroll
  for (int i = 0; i < 3; i++)
    #pragma unroll
    for (int j = 0; j < 2; j++)
      #pragma unroll
      for (int e = 0; e < 16; e++) acc[i][j][e] = 0.f;

  bf16x8 wreg[3][2][2];
  bf16x8 afrP[2][3][2];   // prefetched rr=0..2 for phase parity
  bf16x8 afrC[2][2];      // rr=3,4 loaded at phase top

  // prologue: x(grp0) -> xr0; w(phase0) -> regs
  #pragma unroll
  for (int j = 0; j < 4; j++)
    load_lds16(xbase + xoff[j], xr0 + ((j * 256 + wid * 64) << 4));
  load_lds16(xbase + xoff[4], xr0 + (1024 << 4));
  #pragma unroll
  for (int dy = 0; dy < 3; dy++)
    #pragma unroll
    for (int j = 0; j < 2; j++)
      #pragma unroll
      for (int kk = 0; kk < 2; kk++)
        wreg[dy][j][kk] = *(const bf16x8*)(wlb + dy * 4096 + j * 1024 + kk * 16);

#define PH(S)                                                                      \
  {                                                                                \
    constexpr int grp_ = (S) / 3, dx_ = (S) % 3;                                   \
    constexpr int cur_ = (S) & 1, nxt_ = ((S) + 1) & 1;                            \
    /* x prefetch for next grp at top of dx=0 phase (FIFO: x first) */             \
    if constexpr (dx_ == 0 && grp_ < 3) {                                          \
      char* xd_ = (((grp_ + 1) & 1) ? xr1 : xr0);                                  \
      const __hip_bfloat16* xsrc = xbase + (size_t)(grp_ + 1) * 307328;            \
      _Pragma("unroll")                                                            \
      for (int j = 0; j < 4; j++)                                                  \
        load_lds16(xsrc + xoff[j], xd_ + ((j * 256 + wid * 64) << 4));             \
      load_lds16(xsrc + xoff[4], xd_ + (1024 << 4));                               \
    }                                                                              \
    if constexpr ((S) == 0) {                                                      \
      asm volatile("s_waitcnt vmcnt(17)" ::: "memory");                            \
      __builtin_amdgcn_s_barrier();                                                \
      _Pragma("unroll")                                                            \
      for (int rr = 0; rr < 3; rr++)                                               \
        _Pragma("unroll")                                                          \
        for (int kk = 0; kk < 2; kk++)                                             \
          afrP[0][rr][kk] = *(const bf16x8*)(xp0 + rr * 2176 + kk * 1088);         \
    }                                                                              \
    /* afrC (rr=3,4) for current phase -- first reads after any barrier */         \
    {                                                                              \
      const char* xw_ = ((grp_ & 1) ? xp1 : xp0);                                  \
      _Pragma("unroll")                                                            \
      for (int rr = 0; rr < 2; rr++)                                               \
        _Pragma("unroll")                                                          \
        for (int kk = 0; kk < 2; kk++)                                             \
          afrC[rr][kk] =                                                           \
              *(const bf16x8*)(xw_ + (rr + 3) * 2176 + kk * 1088 + dx_ * 16);      \
    }                                                                              \
    _Pragma("unroll")                                                              \
    for (int dy = 0; dy < 3; dy++) {                                               \
      __builtin_amdgcn_s_setprio(1);                                               \
      _Pragma("unroll")                                                            \
      for (int kk = 0; kk < 2; kk++)                                               \
        _Pragma("unroll")                                                          \
        for (int i = 0; i < 3; i++)                                                \
          _Pragma("unroll")                                                        \
          for (int j = 0; j < 2; j++)                                              \
            acc[i][j] = __builtin_amdgcn_mfma_f32_32x32x16_bf16(                   \
                (i + dy < 3) ? afrP[cur_][(i + dy) % 3][kk]                        \
                             : afrC[(i + dy) - 3][kk],                             \
                wreg[dy][j][kk], acc[i][j], 0, 0, 0);                              \
      __builtin_amdgcn_s_setprio(0);                                               \
      if constexpr ((S) < 11) {                                                    \
        constexpr int sn_ = (S) + 1;                                               \
        constexpr int g2_ = sn_ / 3, dxn_ = sn_ % 3;                               \
        _Pragma("unroll")                                                          \
        for (int j = 0; j < 2; j++)                                                \
          _Pragma("unroll")                                                        \
          for (int kk = 0; kk < 2; kk++)                                           \
            wreg[dy][j][kk] = *(const bf16x8*)(wlb + g2_ * 36864 +                 \
                (dxn_ * 3 + dy) * 4096 + j * 1024 + kk * 16);                      \
        if (dy == 0) {                                                             \
          const char* xw2_ = ((g2_ & 1) ? xp1 : xp0);                              \
          _Pragma("unroll")                                                        \
          for (int rr = 0; rr < 3; rr++)                                           \
            _Pragma("unroll")                                                      \
            for (int kk = 0; kk < 2; kk++)                                         \
              afrP[nxt_][rr][kk] =                                                 \
                  *(const bf16x8*)(xw2_ + rr * 2176 + kk * 1088 + dxn_ * 16);      \
        }                                                                          \
      }                                                                            \
    }                                                                              \
    /* boundary: certify x(g+1) landed + all waves past old-buffer reads */        \
    if constexpr (dx_ == 1 && grp_ < 3) {                                          \
      asm volatile("s_waitcnt lgkmcnt(0)" ::: "memory");                           \
      asm volatile("s_waitcnt vmcnt(24)" ::: "memory");                            \
      __builtin_amdgcn_s_barrier();                                                \
    }                                                                              \
  }

  PH(0)  PH(1)  PH(2)
  PH(3)  PH(4)  PH(5)
  PH(6)  PH(7)  PH(8)
  PH(9)  PH(10) PH(11)
#undef PH

  // epilogue: acc[i][j] covers h-row (h0+wm*3+i), oc = wn*64+j*32+l31
  #pragma unroll
  for (int i = 0; i < 3; i++) {
    int h = h0 + wm * 3 + i;
    #pragma unroll
    for (int j = 0; j < 2; j++) {
      int oc = wn * 64 + j * 32 + l31;
      float* op = out + ((size_t)b * 128 + oc) * 9216 + h * 96 + w0 + 4 * lh;
      #pragma unroll
      for (int qq = 0; qq < 4; qq++) {
        f32x4 v = {acc[i][j][4 * qq + 0], acc[i][j][4 * qq + 1],
                   acc[i][j][4 * qq + 2], acc[i][j][4 * qq + 3]};
        *(f32x4*)(op + 8 * qq) = v;
      }
    }
  }
}

extern "C" void kernel_launch(void* const* d_in, const int* in_sizes, int n_in,
                              void* d_out, int out_size, void* d_ws, size_t ws_size,
                              hipStream_t stream) {
  const float* x   = (const float*)d_in[0];
  const float* z   = (const float*)d_in[1];
  const float* bw  = (const float*)d_in[2];
  const float* gw  = (const float*)d_in[3];
  const float* pww = (const float*)d_in[4];
  const float* dww = (const float*)d_in[5];
  float* out = (float*)d_out;

  char* ws = (char*)d_ws;
  __hip_bfloat16* xn = (__hip_bfloat16*)ws;                       // 78,675,968 B (padded)
  __hip_bfloat16* Wt = (__hip_bfloat16*)(ws + 78675968);          //  9,437,184 B

  hipLaunchKernelGGL(prep_x_kernel, dim3(96, 32), dim3(512), 0, stream, x, xn);
  hipLaunchKernelGGL(prep_w_kernel, dim3(128), dim3(256), 0, stream,
                     z, gw, pww, dww, bw, Wt);
  hipLaunchKernelGGL(conv_kernel,   dim3(1536), dim3(256), 0, stream, xn, Wt, out);
}

// Round 12
// 174.353 us; speedup vs baseline: 1.0061x; 1.0061x over previous
//
#include <hip/hip_runtime.h>
#include <hip/hip_bf16.h>

typedef __bf16 bf16x8 __attribute__((ext_vector_type(8)));
typedef float f32x4 __attribute__((ext_vector_type(4)));
typedef float f32x16 __attribute__((ext_vector_type(16)));

__device__ __forceinline__ void load_lds16(const void* g, void* l) {
  __builtin_amdgcn_global_load_lds((const __attribute__((address_space(1))) void*)g,
                                   (__attribute__((address_space(3))) void*)l, 16, 0, 0);
}

// ---------- prep_x: f32 NCHW -> bf16 padded [b][grp4][98][98][32ic], border-zero fused ----------
__global__ __launch_bounds__(512) void prep_x_kernel(const float* __restrict__ x,
                                                     __hip_bfloat16* __restrict__ xn) {
  __shared__ float tile[128][97];
  int h = blockIdx.x;   // 0..95
  int b = blockIdx.y;   // 0..31
  const float* src = x + (size_t)b * 128 * 9216 + h * 96;
  for (int f = threadIdx.x; f < 3072; f += 512) {   // 128 ic x 24 float4
    int ic = f / 24, w4 = f - ic * 24;
    float4 v = *(const float4*)(src + (size_t)ic * 9216 + w4 * 4);
    tile[ic][w4 * 4 + 0] = v.x; tile[ic][w4 * 4 + 1] = v.y;
    tile[ic][w4 * 4 + 2] = v.z; tile[ic][w4 * 4 + 3] = v.w;
  }
  __syncthreads();
  __hip_bfloat16* bb  = xn + (size_t)b * 4 * 307328;
  __hip_bfloat16* dst = bb + (h + 1) * 3136 + 32;
  for (int o = threadIdx.x; o < 1536; o += 512) {   // 16B units
    int grp = o / 384, rem = o - grp * 384;
    int w = rem >> 2, chunk = rem & 3;
    __hip_bfloat16 tmp[8];
    #pragma unroll
    for (int e = 0; e < 8; e++) tmp[e] = __float2bfloat16(tile[grp * 32 + chunk * 8 + e][w]);
    *(uint4*)(dst + (size_t)grp * 307328 + w * 32 + chunk * 8) = *(uint4*)tmp;
  }
  // left/right halo cells of this row (ph = h+1)
  if (threadIdx.x < 32) {
    int u = threadIdx.x;
    int grp = u >> 3, rem = u & 7;
    int pw = (rem >> 2) ? 97 : 0, k = rem & 3;
    *(uint4*)(bb + (size_t)grp * 307328 + ((h + 1) * 98 + pw) * 32 + k * 8) = make_uint4(0, 0, 0, 0);
  }
  // top/bottom halo rows
  if (h == 0 || h == 95) {
    int ph = (h == 0) ? 0 : 97;
    for (int u = threadIdx.x; u < 1568; u += 512) {
      int grp = u / 392, rem = u - grp * 392;
      int pw = rem >> 2, k = rem & 3;
      *(uint4*)(bb + (size_t)grp * 307328 + (ph * 98 + pw) * 32 + k * 8) = make_uint4(0, 0, 0, 0);
    }
  }
}

// ---------- prep_w fused: z projections + merge -> Wt[b][grp4][dx3][dy3][oc128][32ic] ----------
__global__ __launch_bounds__(256) void prep_w_kernel(
    const float* __restrict__ z, const float* __restrict__ gw,
    const float* __restrict__ pww, const float* __restrict__ dww,
    const float* __restrict__ base, __hip_bfloat16* __restrict__ Wt) {
  __shared__ float zs[2048];
  __shared__ float res[138][33];   // row 0=gate, 1..9=dw taps, 10..137=pw ic
  int oc = blockIdx.x;             // 0..127
  for (int i = threadIdx.x; i < 2048; i += 256) zs[i] = z[i];
  __syncthreads();
  int row = threadIdx.x;
  if (row < 138) {
    const float* wrow = (row == 0) ? gw + (size_t)oc * 64
                      : (row < 10) ? dww + ((size_t)oc * 9 + (row - 1)) * 64
                                   : pww + ((size_t)oc * 128 + (row - 10)) * 64;
    float wr[64];
    #pragma unroll
    for (int i = 0; i < 16; i++) {
      float4 v = ((const float4*)wrow)[i];
      wr[4*i] = v.x; wr[4*i+1] = v.y; wr[4*i+2] = v.z; wr[4*i+3] = v.w;
    }
    for (int b = 0; b < 32; b++) {
      float a = 0.f;
      #pragma unroll
      for (int i = 0; i < 64; i++) a += zs[b * 64 + i] * wr[i];
      res[row][b] = a;
    }
  }
  __syncthreads();
  for (int e = threadIdx.x; e < 18432; e += 256) {   // bf162 units
    int icp = e & 15;
    int r1 = e >> 4;
    int tap = r1 % 9, bg = r1 / 9;       // bg = b*4+grp
    int grp = bg & 3, b = bg >> 2;
    int ic = grp * 32 + icp * 2;
    int dy = tap / 3, dx = tap - dy * 3;
    float g = res[0][b], d = res[1 + tap][b];
    float p0 = res[10 + ic][b], p1 = res[11 + ic][b];
    const float* bp = base + ((size_t)(oc * 128 + ic)) * 9 + tap;
    __hip_bfloat162 o2 = {__float2bfloat16(bp[0] * g + p0 * d),
                          __float2bfloat16(bp[9] * g + p1 * d)};
    // slot = dx*3 + dy  (dx-major for dx-outer conv phases)
    *(__hip_bfloat162*)(Wt + (((size_t)bg * 9 + dx * 3 + dy) * 128 + oc) * 32 + icp * 2) = o2;
  }
}

// ---------- conv: 384px x 64oc per block, waves = 192px x 32oc, 32x32x16 MFMA ----------
// Weight VMEM traffic cut 4x: each wave reads only a 32-oc slice (6 loads/phase).
// x: LDS dbuf chunk-major [hh14][chunk4][ww34][16B]; x(g+1) issued top of dx=0
// (target buffer certified free by grp-boundary barrier at end of dx=2).
__global__ __launch_bounds__(256, 2) void conv_kernel(
    const __hip_bfloat16* __restrict__ xn, const __hip_bfloat16* __restrict__ Wt,
    float* __restrict__ out) {
  __shared__ __align__(16) char smem[65536];   // 2 x 32768 B x-tiles (30464 used + pad)

  int bid = blockIdx.x;
  int X = bid & 7, q = bid >> 3;       // XCD pin: 192 blocks (4 samples) per XCD
  int logical = X * 192 + q;
  int b   = logical / 48;
  int rem = logical - b * 48;          // 48 = 8 hr x 3 wc x 2 ocg
  int ocg = rem & 1;
  int t24 = rem >> 1;
  int hr  = t24 / 3;
  int wc  = t24 - hr * 3;
  int h0 = hr * 12, w0 = wc * 32;

  int tid = threadIdx.x;
  int lane = tid & 63, wid = tid >> 6;
  int l31 = lane & 31, lh = lane >> 5;
  int wm = wid >> 1, wn = wid & 1;

  char* const xr0 = smem;
  char* const xr1 = smem + 32768;
  // per-lane A-read bases: + rr*2176 + kk*1088 + dx*16  (rr = i+dy in [0,8))
  const char* xp0 = xr0 + wm * 6 * 2176 + l31 * 16 + lh * 544;
  const char* xp1 = xr1 + wm * 6 * 2176 + l31 * 16 + lh * 544;

  // x-stage source offsets: 1904 slots ([hh14][chunk4][ww34]), 8 sweeps, clamp tail
  int xoff[8];
  #pragma unroll
  for (int j = 0; j < 8; j++) {
    int t = j * 256 + tid; if (t > 1903) t = 1903;
    int hh = t / 136, r2 = t - hh * 136;
    int k = r2 / 34, ww = r2 - k * 34;
    xoff[j] = ((h0 + hh) * 98 + (w0 + ww)) * 32 + k * 8;
  }

  const __hip_bfloat16* xbase = xn + (size_t)b * 4 * 307328;
  // per-lane weight base: oc = ocg*64 + wn*32 + l31, ic chunk lh
  const __hip_bfloat16* wlb =
      Wt + (size_t)b * 147456 + (ocg * 64 + wn * 32 + l31) * 32 + lh * 8;

  f32x16 acc[6];
  #pragma unroll
  for (int i = 0; i < 6; i++)
    #pragma unroll
    for (int e = 0; e < 16; e++) acc[i][e] = 0.f;

  bf16x8 wreg[3][2];

  // prologue: x(grp0) -> xr0; w(phase0) -> regs
  #pragma unroll
  for (int j = 0; j < 8; j++)
    load_lds16(xbase + xoff[j], xr0 + ((j * 256 + wid * 64) << 4));
  #pragma unroll
  for (int dy = 0; dy < 3; dy++)
    #pragma unroll
    for (int kk = 0; kk < 2; kk++)
      wreg[dy][kk] = *(const bf16x8*)(wlb + dy * 4096 + kk * 16);

#define PH(S)                                                                      \
  {                                                                                \
    constexpr int grp_ = (S) / 3, dx_ = (S) % 3;                                   \
    /* x prefetch for next grp: target buffer certified free by last barrier */    \
    if constexpr (dx_ == 0 && grp_ < 3) {                                          \
      char* xd_ = (((grp_ + 1) & 1) ? xr1 : xr0);                                  \
      const __hip_bfloat16* xsrc = xbase + (size_t)(grp_ + 1) * 307328;            \
      _Pragma("unroll")                                                            \
      for (int j = 0; j < 8; j++)                                                  \
        load_lds16(xsrc + xoff[j], xd_ + ((j * 256 + wid * 64) << 4));             \
    }                                                                              \
    if constexpr ((S) == 0) {                                                      \
      asm volatile("s_waitcnt vmcnt(14)" ::: "memory");                            \
      __builtin_amdgcn_s_barrier();                                                \
    }                                                                              \
    const char* xw_ = ((grp_ & 1) ? xp1 : xp0);                                    \
    bf16x8 afr[8][2];                                                              \
    _Pragma("unroll")                                                              \
    for (int rr = 0; rr < 8; rr++)                                                 \
      _Pragma("unroll")                                                            \
      for (int kk = 0; kk < 2; kk++)                                               \
        afr[rr][kk] = *(const bf16x8*)(xw_ + rr * 2176 + kk * 1088 + dx_ * 16);    \
    _Pragma("unroll")                                                              \
    for (int dy = 0; dy < 3; dy++) {                                               \
      __builtin_amdgcn_s_setprio(1);                                               \
      _Pragma("unroll")                                                            \
      for (int kk = 0; kk < 2; kk++)                                               \
        _Pragma("unroll")                                                          \
        for (int i = 0; i < 6; i++)                                                \
          acc[i] = __builtin_amdgcn_mfma_f32_32x32x16_bf16(afr[i + dy][kk],        \
                        wreg[dy][kk], acc[i], 0, 0, 0);                            \
      __builtin_amdgcn_s_setprio(0);                                               \
      if constexpr ((S) < 11) {                                                    \
        constexpr int sn_ = (S) + 1;                                               \
        constexpr int g2_ = sn_ / 3, dxn_ = sn_ % 3;                               \
        _Pragma("unroll")                                                          \
        for (int kk = 0; kk < 2; kk++)                                             \
          wreg[dy][kk] = *(const bf16x8*)(wlb + g2_ * 36864 +                      \
              (dxn_ * 3 + dy) * 4096 + kk * 16);                                   \
      }                                                                            \
    }                                                                              \
    /* grp boundary: everyone done reading this grp's buffer; x(g+1) already */    \
    /* certified landed by the in-order vmcnt drains of the weight consumes */     \
    if constexpr (dx_ == 2 && grp_ < 3) {                                          \
      __builtin_amdgcn_s_barrier();                                                \
    }                                                                              \
  }

  PH(0)  PH(1)  PH(2)
  PH(3)  PH(4)  PH(5)
  PH(6)  PH(7)  PH(8)
  PH(9)  PH(10) PH(11)
#undef PH

  // epilogue: acc[i] covers h-row (h0+wm*6+i), oc = ocg*64+wn*32+l31
  #pragma unroll
  for (int i = 0; i < 6; i++) {
    int h = h0 + wm * 6 + i;
    int oc = ocg * 64 + wn * 32 + l31;
    float* op = out + ((size_t)b * 128 + oc) * 9216 + h * 96 + w0 + 4 * lh;
    #pragma unroll
    for (int qq = 0; qq < 4; qq++) {
      f32x4 v = {acc[i][4 * qq + 0], acc[i][4 * qq + 1],
                 acc[i][4 * qq + 2], acc[i][4 * qq + 3]};
      *(f32x4*)(op + 8 * qq) = v;
    }
  }
}

extern "C" void kernel_launch(void* const* d_in, const int* in_sizes, int n_in,
                              void* d_out, int out_size, void* d_ws, size_t ws_size,
                              hipStream_t stream) {
  const float* x   = (const float*)d_in[0];
  const float* z   = (const float*)d_in[1];
  const float* bw  = (const float*)d_in[2];
  const float* gw  = (const float*)d_in[3];
  const float* pww = (const float*)d_in[4];
  const float* dww = (const float*)d_in[5];
  float* out = (float*)d_out;

  char* ws = (char*)d_ws;
  __hip_bfloat16* xn = (__hip_bfloat16*)ws;                       // 78,675,968 B (padded)
  __hip_bfloat16* Wt = (__hip_bfloat16*)(ws + 78675968);          //  9,437,184 B

  hipLaunchKernelGGL(prep_x_kernel, dim3(96, 32), dim3(512), 0, stream, x, xn);
  hipLaunchKernelGGL(prep_w_kernel, dim3(128), dim3(256), 0, stream,
                     z, gw, pww, dww, bw, Wt);
  hipLaunchKernelGGL(conv_kernel,   dim3(1536), dim3(256), 0, stream, xn, Wt, out);
}

// Round 13
// 152.827 us; speedup vs baseline: 1.1478x; 1.1409x over previous
//
#include <hip/hip_runtime.h>
#include <hip/hip_bf16.h>

typedef __bf16 bf16x8 __attribute__((ext_vector_type(8)));
typedef float f32x4 __attribute__((ext_vector_type(4)));
typedef float f32x16 __attribute__((ext_vector_type(16)));

__device__ __forceinline__ void load_lds16(const void* g, void* l) {
  __builtin_amdgcn_global_load_lds((const __attribute__((address_space(1))) void*)g,
                                   (__attribute__((address_space(3))) void*)l, 16, 0, 0);
}

// ---------- prep_x: f32 NCHW -> bf16 padded [b][grp4][98][98][32ic], border-zero fused ----------
__global__ __launch_bounds__(512) void prep_x_kernel(const float* __restrict__ x,
                                                     __hip_bfloat16* __restrict__ xn) {
  __shared__ float tile[128][97];
  int h = blockIdx.x;   // 0..95
  int b = blockIdx.y;   // 0..31
  const float* src = x + (size_t)b * 128 * 9216 + h * 96;
  for (int f = threadIdx.x; f < 3072; f += 512) {   // 128 ic x 24 float4
    int ic = f / 24, w4 = f - ic * 24;
    float4 v = *(const float4*)(src + (size_t)ic * 9216 + w4 * 4);
    tile[ic][w4 * 4 + 0] = v.x; tile[ic][w4 * 4 + 1] = v.y;
    tile[ic][w4 * 4 + 2] = v.z; tile[ic][w4 * 4 + 3] = v.w;
  }
  __syncthreads();
  __hip_bfloat16* bb  = xn + (size_t)b * 4 * 307328;
  __hip_bfloat16* dst = bb + (h + 1) * 3136 + 32;
  for (int o = threadIdx.x; o < 1536; o += 512) {   // 16B units
    int grp = o / 384, rem = o - grp * 384;
    int w = rem >> 2, chunk = rem & 3;
    __hip_bfloat16 tmp[8];
    #pragma unroll
    for (int e = 0; e < 8; e++) tmp[e] = __float2bfloat16(tile[grp * 32 + chunk * 8 + e][w]);
    *(uint4*)(dst + (size_t)grp * 307328 + w * 32 + chunk * 8) = *(uint4*)tmp;
  }
  // left/right halo cells of this row (ph = h+1)
  if (threadIdx.x < 32) {
    int u = threadIdx.x;
    int grp = u >> 3, rem = u & 7;
    int pw = (rem >> 2) ? 97 : 0, k = rem & 3;
    *(uint4*)(bb + (size_t)grp * 307328 + ((h + 1) * 98 + pw) * 32 + k * 8) = make_uint4(0, 0, 0, 0);
  }
  // top/bottom halo rows
  if (h == 0 || h == 95) {
    int ph = (h == 0) ? 0 : 97;
    for (int u = threadIdx.x; u < 1568; u += 512) {
      int grp = u / 392, rem = u - grp * 392;
      int pw = rem >> 2, k = rem & 3;
      *(uint4*)(bb + (size_t)grp * 307328 + (ph * 98 + pw) * 32 + k * 8) = make_uint4(0, 0, 0, 0);
    }
  }
}

// ---------- prep_w: grid 1024 = (oc 128) x (8 groups of 4 samples) ----------
__global__ __launch_bounds__(256) void prep_w_kernel(
    const float* __restrict__ z, const float* __restrict__ gw,
    const float* __restrict__ pww, const float* __restrict__ dww,
    const float* __restrict__ base, __hip_bfloat16* __restrict__ Wt) {
  __shared__ float zs[256];
  __shared__ float res[138][5];   // row 0=gate, 1..9=dw taps, 10..137=pw ic; 4 b cols
  int oc = blockIdx.x & 127;
  int b0 = (blockIdx.x >> 7) * 4;
  zs[threadIdx.x] = z[b0 * 64 + threadIdx.x];
  __syncthreads();
  int row = threadIdx.x;
  if (row < 138) {
    const float* wrow = (row == 0) ? gw + (size_t)oc * 64
                      : (row < 10) ? dww + ((size_t)oc * 9 + (row - 1)) * 64
                                   : pww + ((size_t)oc * 128 + (row - 10)) * 64;
    float wr[64];
    #pragma unroll
    for (int i = 0; i < 16; i++) {
      float4 v = ((const float4*)wrow)[i];
      wr[4*i] = v.x; wr[4*i+1] = v.y; wr[4*i+2] = v.z; wr[4*i+3] = v.w;
    }
    #pragma unroll
    for (int bb = 0; bb < 4; bb++) {
      float a = 0.f;
      #pragma unroll
      for (int i = 0; i < 64; i++) a += zs[bb * 64 + i] * wr[i];
      res[row][bb] = a;
    }
  }
  __syncthreads();
  for (int e = threadIdx.x; e < 2304; e += 256) {   // bf162 units
    int icp = e & 15;
    int r1 = e >> 4;                  // 0..143
    int tap = r1 % 9, gb = r1 / 9;    // gb = bb*4+grp
    int grp = gb & 3, bb = gb >> 2;
    int b = b0 + bb;
    int ic = grp * 32 + icp * 2;
    int dy = tap / 3, dx = tap - dy * 3;
    float g = res[0][bb], d = res[1 + tap][bb];
    float p0 = res[10 + ic][bb], p1 = res[11 + ic][bb];
    const float* bp = base + ((size_t)(oc * 128 + ic)) * 9 + tap;
    __hip_bfloat162 o2 = {__float2bfloat16(bp[0] * g + p0 * d),
                          __float2bfloat16(bp[9] * g + p1 * d)};
    // slot = dx*3 + dy  (dx-major for dx-outer conv phases)
    *(__hip_bfloat162*)(Wt + ((((size_t)(b * 4 + grp)) * 9 + dx * 3 + dy) * 128 + oc) * 32 + icp * 2) = o2;
  }
}

// ---------- conv: 256px x 64oc per block, waves = 128px x 32oc, 32x32x16 MFMA ----------
// 12 waves/CU (3 blocks x 4 waves). Weights reg-staged lag-1; x LDS dbuf chunk-major.
__global__ __launch_bounds__(256, 3) void conv_kernel(
    const __hip_bfloat16* __restrict__ xn, const __hip_bfloat16* __restrict__ Wt,
    float* __restrict__ out) {
  __shared__ __align__(16) char smem[49152];   // 2 x 24576 B x-tiles (21760 used + pad)

  int bid = blockIdx.x;
  int X = bid & 7, q = bid >> 3;       // XCD pin: 288 blocks (4 samples) per XCD
  int logical = X * 288 + q;
  int b   = logical / 72;
  int rem = logical - b * 72;          // 72 = 12 hr x 3 wc x 2 ocg
  int ocg = rem & 1;
  int t36 = rem >> 1;
  int hr  = t36 / 3;
  int wc  = t36 - hr * 3;
  int h0 = hr * 8, w0 = wc * 32;

  int tid = threadIdx.x;
  int lane = tid & 63, wid = tid >> 6;
  int l31 = lane & 31, lh = lane >> 5;
  int wm = wid >> 1, wn = wid & 1;

  char* const xr0 = smem;
  char* const xr1 = smem + 24576;
  // per-lane A-read bases: + rr*2176 + kk*1088 + dx*16  (rr = i+dy in [0,6))
  const char* xp0 = xr0 + wm * 4 * 2176 + l31 * 16 + lh * 544;
  const char* xp1 = xr1 + wm * 4 * 2176 + l31 * 16 + lh * 544;

  // x-stage source offsets: 1360 slots ([hh10][chunk4][ww34]), 6 sweeps, clamp tail
  int xoff[6];
  #pragma unroll
  for (int j = 0; j < 6; j++) {
    int t = j * 256 + tid; if (t > 1359) t = 1359;
    int hh = t / 136, r2 = t - hh * 136;
    int k = r2 / 34, ww = r2 - k * 34;
    xoff[j] = ((h0 + hh) * 98 + (w0 + ww)) * 32 + k * 8;
  }

  const __hip_bfloat16* xbase = xn + (size_t)b * 4 * 307328;
  // per-lane weight base: oc = ocg*64 + wn*32 + l31, ic chunk lh
  const __hip_bfloat16* wlb =
      Wt + (size_t)b * 147456 + (ocg * 64 + wn * 32 + l31) * 32 + lh * 8;

  f32x16 acc[4];
  #pragma unroll
  for (int i = 0; i < 4; i++)
    #pragma unroll
    for (int e = 0; e < 16; e++) acc[i][e] = 0.f;

  bf16x8 wreg[3][2];

  // prologue: x(grp0) -> xr0; w(phase0) -> regs
  #pragma unroll
  for (int j = 0; j < 6; j++)
    load_lds16(xbase + xoff[j], xr0 + ((j * 256 + wid * 64) << 4));
  #pragma unroll
  for (int dy = 0; dy < 3; dy++)
    #pragma unroll
    for (int kk = 0; kk < 2; kk++)
      wreg[dy][kk] = *(const bf16x8*)(wlb + dy * 4096 + kk * 16);

#define PH(S)                                                                      \
  {                                                                                \
    constexpr int grp_ = (S) / 3, dx_ = (S) % 3;                                   \
    /* x prefetch for next grp: target buffer certified free by last barrier */    \
    if constexpr (dx_ == 0 && grp_ < 3) {                                          \
      char* xd_ = (((grp_ + 1) & 1) ? xr1 : xr0);                                  \
      const __hip_bfloat16* xsrc = xbase + (size_t)(grp_ + 1) * 307328;            \
      _Pragma("unroll")                                                            \
      for (int j = 0; j < 6; j++)                                                  \
        load_lds16(xsrc + xoff[j], xd_ + ((j * 256 + wid * 64) << 4));             \
    }                                                                              \
    if constexpr ((S) == 0) {                                                      \
      asm volatile("s_waitcnt vmcnt(12)" ::: "memory");                            \
      __builtin_amdgcn_s_barrier();                                                \
    }                                                                              \
    const char* xw_ = ((grp_ & 1) ? xp1 : xp0);                                    \
    bf16x8 afr[6][2];                                                              \
    _Pragma("unroll")                                                              \
    for (int rr = 0; rr < 6; rr++)                                                 \
      _Pragma("unroll")                                                            \
      for (int kk = 0; kk < 2; kk++)                                               \
        afr[rr][kk] = *(const bf16x8*)(xw_ + rr * 2176 + kk * 1088 + dx_ * 16);    \
    _Pragma("unroll")                                                              \
    for (int dy = 0; dy < 3; dy++) {                                               \
      __builtin_amdgcn_s_setprio(1);                                               \
      _Pragma("unroll")                                                            \
      for (int kk = 0; kk < 2; kk++)                                               \
        _Pragma("unroll")                                                          \
        for (int i = 0; i < 4; i++)                                                \
          acc[i] = __builtin_amdgcn_mfma_f32_32x32x16_bf16(afr[i + dy][kk],        \
                        wreg[dy][kk], acc[i], 0, 0, 0);                            \
      __builtin_amdgcn_s_setprio(0);                                               \
      if constexpr ((S) < 11) {                                                    \
        constexpr int sn_ = (S) + 1;                                               \
        constexpr int g2_ = sn_ / 3, dxn_ = sn_ % 3;                               \
        _Pragma("unroll")                                                          \
        for (int kk = 0; kk < 2; kk++)                                             \
          wreg[dy][kk] = *(const bf16x8*)(wlb + g2_ * 36864 +                      \
              (dxn_ * 3 + dy) * 4096 + kk * 16);                                   \
      }                                                                            \
    }                                                                              \
    /* grp boundary: everyone done reading this grp's buffer; x(g+1) already */    \
    /* certified landed by the in-order vmcnt drains of the weight consumes */     \
    if constexpr (dx_ == 2 && grp_ < 3) {                                          \
      __builtin_amdgcn_s_barrier();                                                \
    }                                                                              \
  }

  PH(0)  PH(1)  PH(2)
  PH(3)  PH(4)  PH(5)
  PH(6)  PH(7)  PH(8)
  PH(9)  PH(10) PH(11)
#undef PH

  // epilogue: acc[i] covers h-row (h0+wm*4+i), oc = ocg*64+wn*32+l31
  #pragma unroll
  for (int i = 0; i < 4; i++) {
    int h = h0 + wm * 4 + i;
    int oc = ocg * 64 + wn * 32 + l31;
    float* op = out + ((size_t)b * 128 + oc) * 9216 + h * 96 + w0 + 4 * lh;
    #pragma unroll
    for (int qq = 0; qq < 4; qq++) {
      f32x4 v = {acc[i][4 * qq + 0], acc[i][4 * qq + 1],
                 acc[i][4 * qq + 2], acc[i][4 * qq + 3]};
      *(f32x4*)(op + 8 * qq) = v;
    }
  }
}

extern "C" void kernel_launch(void* const* d_in, const int* in_sizes, int n_in,
                              void* d_out, int out_size, void* d_ws, size_t ws_size,
                              hipStream_t stream) {
  const float* x   = (const float*)d_in[0];
  const float* z   = (const float*)d_in[1];
  const float* bw  = (const float*)d_in[2];
  const float* gw  = (const float*)d_in[3];
  const float* pww = (const float*)d_in[4];
  const float* dww = (const float*)d_in[5];
  float* out = (float*)d_out;

  char* ws = (char*)d_ws;
  __hip_bfloat16* xn = (__hip_bfloat16*)ws;                       // 78,675,968 B (padded)
  __hip_bfloat16* Wt = (__hip_bfloat16*)(ws + 78675968);          //  9,437,184 B

  hipLaunchKernelGGL(prep_x_kernel, dim3(96, 32), dim3(512), 0, stream, x, xn);
  hipLaunchKernelGGL(prep_w_kernel, dim3(1024), dim3(256), 0, stream,
                     z, gw, pww, dww, bw, Wt);
  hipLaunchKernelGGL(conv_kernel,   dim3(2304), dim3(256), 0, stream, xn, Wt, out);
}